// Round 10
// baseline (53.946 us; speedup 1.0000x reference)
//
#include <hip/hip_runtime.h>
#include <stdint.h>

#define INF 8192        // IN features
#define OUTF 8192       // OUT features
#define TOK 16          // tokens (2*8)
#define KSPLIT 4
#define KR (INF / KSPLIT)          // 2048 K per block
#define NI (KR / 32)               // 64 MFMA iters per wave
#define ROWS_PER_BLOCK 128         // 8 waves * 16 rows (512 threads)
#define LDS_STRIDE (KR + 8)        // bf16 elems, padded (2056)
#define NRG (OUTF / ROWS_PER_BLOCK)   // 64 row groups -> grid 256 = 1 block/CU

typedef __attribute__((ext_vector_type(8))) short short8;
typedef __attribute__((ext_vector_type(4))) short short4v;
typedef __attribute__((ext_vector_type(4))) float float4v;
typedef __attribute__((ext_vector_type(4))) int int4v;
typedef __attribute__((ext_vector_type(4))) uint32_t uint4v;

__device__ __forceinline__ short f2bf(float f) {
    uint32_t u = __builtin_bit_cast(uint32_t, f);
    u += 0x7fffu + ((u >> 16) & 1u);   // round-to-nearest-even
    return (short)(u >> 16);
}

// pack two floats to 2 bf16 (round-half-up) in one u32: a->low, b->high
__device__ __forceinline__ uint32_t pkbf(float a, float b) {
    uint32_t ua = __builtin_bit_cast(uint32_t, a) + 0x8000u;
    uint32_t ub = __builtin_bit_cast(uint32_t, b) + 0x8000u;
    return (ua >> 16) | (ub & 0xffff0000u);
}

// Stage x[0..15][k0..k0+KR) into LDS as bf16 (padded stride). 512 threads.
__device__ __forceinline__ void stage_x(const float* __restrict__ x, short* xs,
                                        int k0, int tid) {
    #pragma unroll
    for (int it = 0; it < (TOK * KR / 4) / 512; ++it) {   // 16 iters
        int idx = tid + it * 512;
        int t  = idx >> 9;        // KR/4 = 512 float4 per token row
        int kq = idx & 511;
        float4v xv = *reinterpret_cast<const float4v*>(x + (size_t)t * INF + k0 + kq * 4);
        short4v h;
        h[0] = f2bf(xv[0]); h[1] = f2bf(xv[1]); h[2] = f2bf(xv[2]); h[3] = f2bf(xv[3]);
        *reinterpret_cast<short4v*>(xs + t * LDS_STRIDE + kq * 4) = h;
    }
}

// Dequant one 8-code group to a bf16 MFMA B-fragment.
__device__ __forceinline__ short8 dequant8(int4v A, int4v B, float s) {
    float m = -127.0f * s;
    uint4v pk;
    pk[0] = pkbf(fmaf((float)A[0], s, m), fmaf((float)A[1], s, m));
    pk[1] = pkbf(fmaf((float)A[2], s, m), fmaf((float)A[3], s, m));
    pk[2] = pkbf(fmaf((float)B[0], s, m), fmaf((float)B[1], s, m));
    pk[3] = pkbf(fmaf((float)B[2], s, m), fmaf((float)B[3], s, m));
    return __builtin_bit_cast(short8, pk);
}

// ---------------- main split-K kernel (two-dispatch path) ----------------
// R9 structure with 128 rows/block (8 waves): grid = 256 = 1 block/CU,
// one staging prologue per CU, x-tile amortized over 2x the rows.
__global__ __launch_bounds__(512, 2) void gemm_q8_part(
    const float* __restrict__ x, const int* __restrict__ qw,
    const float* __restrict__ scales, float* __restrict__ pbuf)
{
    __shared__ short xs[TOK * LDS_STRIDE];
    int rg = blockIdx.x >> 2;          // 0..63 row groups
    int ks = blockIdx.x & 3;           // 0..3 k splits
    int k0 = ks * KR;
    int tid = threadIdx.x;

    stage_x(x, xs, k0, tid);
    __syncthreads();

    int wave = tid >> 6;               // 0..7
    int lane = tid & 63;
    int col  = lane & 15;
    int kg   = lane >> 4;
    int r0 = rg * ROWS_PER_BLOCK + wave * 16;
    int r  = r0 + col;

    const int*   qrow = qw + (size_t)r * INF + k0 + kg * 8;
    const float* srow = scales + (size_t)r * (INF / 32) + (k0 >> 5);
    const short* aptr = xs + col * LDS_STRIDE + kg * 8;

    int4v A0 = *reinterpret_cast<const int4v*>(qrow);
    int4v B0 = *reinterpret_cast<const int4v*>(qrow + 4);
    int4v A1 = *reinterpret_cast<const int4v*>(qrow + 32);
    int4v B1 = *reinterpret_cast<const int4v*>(qrow + 36);
    float s0 = srow[0], s1 = srow[1];

    float4v acc = {0.f, 0.f, 0.f, 0.f};

    #pragma unroll 4
    for (int i = 0; i < NI; ++i) {
        int ip = (i + 2 < NI) ? (i + 2) : (NI - 1);
        int4v A2 = *reinterpret_cast<const int4v*>(qrow + ip * 32);
        int4v B2 = *reinterpret_cast<const int4v*>(qrow + ip * 32 + 4);
        float s2 = srow[ip];

        short8 bfrag = dequant8(A0, B0, s0);
        short8 afrag = *reinterpret_cast<const short8*>(aptr + i * 32);

        acc = __builtin_amdgcn_mfma_f32_16x16x32_bf16(afrag, bfrag, acc, 0, 0, 0);

        A0 = A1; B0 = B1; s0 = s1;
        A1 = A2; B1 = B2; s1 = s2;
    }

    // C mapping: col = lane&15 (out row r), row = (lane>>4)*4 + i (token t)
    float* pb = pbuf + (size_t)ks * TOK * OUTF;
    #pragma unroll
    for (int i = 0; i < 4; ++i) {
        int t = kg * 4 + i;
        pb[(size_t)t * OUTF + r0 + col] = acc[i];
    }
}

__global__ __launch_bounds__(256) void reduce_bias_k(
    const float* __restrict__ pbuf, const float* __restrict__ bias,
    float* __restrict__ out)
{
    int gid = blockIdx.x * 256 + threadIdx.x;   // 32768 threads, float4 each
    int f = gid * 4;
    int t = f >> 13;       // /8192
    int r = f & (OUTF - 1);
    float4v a = *reinterpret_cast<const float4v*>(bias + r);
    #pragma unroll
    for (int s = 0; s < KSPLIT; ++s) {
        float4v p = *reinterpret_cast<const float4v*>(pbuf + (size_t)(s * TOK + t) * OUTF + r);
        a += p;
    }
    *reinterpret_cast<float4v*>(out + f) = a;
}

// Fallback when d_ws is too small: full-K per block, direct write (+bias).
__global__ __launch_bounds__(512, 2) void gemm_q8_direct(
    const float* __restrict__ x, const int* __restrict__ qw,
    const float* __restrict__ scales, const float* __restrict__ bias,
    float* __restrict__ out)
{
    __shared__ short xs[TOK * LDS_STRIDE];
    int rg = blockIdx.x;               // 0..63
    int tid = threadIdx.x;
    int wave = tid >> 6;
    int lane = tid & 63;
    int col  = lane & 15;
    int kg   = lane >> 4;
    int r0 = rg * ROWS_PER_BLOCK + wave * 16;
    int r  = r0 + col;

    float4v acc = {0.f, 0.f, 0.f, 0.f};
    for (int ks = 0; ks < KSPLIT; ++ks) {
        int k0 = ks * KR;
        __syncthreads();
        stage_x(x, xs, k0, tid);
        __syncthreads();
        const int*   qrow = qw + (size_t)r * INF + k0 + kg * 8;
        const float* srow = scales + (size_t)r * (INF / 32) + (k0 >> 5);
        const short* aptr = xs + col * LDS_STRIDE + kg * 8;

        int4v A0 = *reinterpret_cast<const int4v*>(qrow);
        int4v B0 = *reinterpret_cast<const int4v*>(qrow + 4);
        int4v A1 = *reinterpret_cast<const int4v*>(qrow + 32);
        int4v B1 = *reinterpret_cast<const int4v*>(qrow + 36);
        float s0 = srow[0], s1 = srow[1];

        #pragma unroll 4
        for (int i = 0; i < NI; ++i) {
            int ip = (i + 2 < NI) ? (i + 2) : (NI - 1);
            int4v A2 = *reinterpret_cast<const int4v*>(qrow + ip * 32);
            int4v B2 = *reinterpret_cast<const int4v*>(qrow + ip * 32 + 4);
            float s2 = srow[ip];

            short8 bfrag = dequant8(A0, B0, s0);
            short8 afrag = *reinterpret_cast<const short8*>(aptr + i * 32);
            acc = __builtin_amdgcn_mfma_f32_16x16x32_bf16(afrag, bfrag, acc, 0, 0, 0);

            A0 = A1; B0 = B1; s0 = s1;
            A1 = A2; B1 = B2; s1 = s2;
        }
    }
    #pragma unroll
    for (int i = 0; i < 4; ++i) {
        int t = kg * 4 + i;
        out[(size_t)t * OUTF + r0 + col] = acc[i] + bias[r0 + col];
    }
}

extern "C" void kernel_launch(void* const* d_in, const int* in_sizes, int n_in,
                              void* d_out, int out_size, void* d_ws, size_t ws_size,
                              hipStream_t stream) {
    const float* x      = (const float*)d_in[0];
    const int*   qw     = (const int*)d_in[1];
    const float* scales = (const float*)d_in[2];
    const float* bias   = (const float*)d_in[3];
    float* out = (float*)d_out;

    size_t pbytes = (size_t)KSPLIT * TOK * OUTF * sizeof(float);   // 2 MB
    if (ws_size >= pbytes) {
        float* pbuf = (float*)d_ws;
        gemm_q8_part<<<NRG * KSPLIT, 512, 0, stream>>>(x, qw, scales, pbuf);
        reduce_bias_k<<<(TOK * OUTF / 4) / 256, 256, 0, stream>>>(pbuf, bias, out);
    } else {
        gemm_q8_direct<<<NRG, 512, 0, stream>>>(x, qw, scales, bias, out);
    }
}

// Round 11
// 53.245 us; speedup vs baseline: 1.0132x; 1.0132x over previous
//
#include <hip/hip_runtime.h>
#include <stdint.h>

#define INF 8192        // IN features
#define OUTF 8192       // OUT features
#define TOK 16          // tokens (2*8)
#define KSPLIT 4
#define KR (INF / KSPLIT)          // 2048 K per block
#define NI (KR / 32)               // 64 MFMA iters per wave
#define ROWS_PER_BLOCK 64          // 4 waves * 16 rows
#define LDS_STRIDE (KR + 8)        // bf16 elems, padded (2056)
#define NRG (OUTF / ROWS_PER_BLOCK)   // 128 row groups

typedef __attribute__((ext_vector_type(8))) short short8;
typedef __attribute__((ext_vector_type(4))) short short4v;
typedef __attribute__((ext_vector_type(4))) float float4v;
typedef __attribute__((ext_vector_type(4))) int int4v;
typedef __attribute__((ext_vector_type(4))) uint32_t uint4v;

__device__ __forceinline__ short f2bf(float f) {
    uint32_t u = __builtin_bit_cast(uint32_t, f);
    u += 0x7fffu + ((u >> 16) & 1u);   // round-to-nearest-even
    return (short)(u >> 16);
}

// pack two floats to 2 bf16 (round-half-up) in one u32: a->low, b->high
__device__ __forceinline__ uint32_t pkbf(float a, float b) {
    uint32_t ua = __builtin_bit_cast(uint32_t, a) + 0x8000u;
    uint32_t ub = __builtin_bit_cast(uint32_t, b) + 0x8000u;
    return (ua >> 16) | (ub & 0xffff0000u);
}

// Stage x[0..15][k0..k0+KR) into LDS as bf16 (padded stride).
__device__ __forceinline__ void stage_x(const float* __restrict__ x, short* xs,
                                        int k0, int tid) {
    #pragma unroll
    for (int it = 0; it < (TOK * KR / 4) / 256; ++it) {   // 32 iters
        int idx = tid + it * 256;
        int t  = idx >> 9;        // KR/4 = 512 float4 per token row
        int kq = idx & 511;
        float4v xv = *reinterpret_cast<const float4v*>(x + (size_t)t * INF + k0 + kq * 4);
        short4v h;
        h[0] = f2bf(xv[0]); h[1] = f2bf(xv[1]); h[2] = f2bf(xv[2]); h[3] = f2bf(xv[3]);
        *reinterpret_cast<short4v*>(xs + t * LDS_STRIDE + kq * 4) = h;
    }
}

// Dequant one 8-code group to a bf16 MFMA B-fragment.
__device__ __forceinline__ short8 dequant8(int4v A, int4v B, float s) {
    float m = -127.0f * s;
    uint4v pk;
    pk[0] = pkbf(fmaf((float)A[0], s, m), fmaf((float)A[1], s, m));
    pk[1] = pkbf(fmaf((float)A[2], s, m), fmaf((float)A[3], s, m));
    pk[2] = pkbf(fmaf((float)B[0], s, m), fmaf((float)B[1], s, m));
    pk[3] = pkbf(fmaf((float)B[2], s, m), fmaf((float)B[3], s, m));
    return __builtin_bit_cast(short8, pk);
}

// ---------------- main split-K kernel (two-dispatch path) ----------------
// R2 structure, KSPLIT=4: longer K per block amortizes prologue, halves pbuf.
__global__ __launch_bounds__(256, 2) void gemm_q8_part(
    const float* __restrict__ x, const int* __restrict__ qw,
    const float* __restrict__ scales, float* __restrict__ pbuf)
{
    __shared__ short xs[TOK * LDS_STRIDE];
    int rg = blockIdx.x >> 2;          // 0..127 row groups
    int ks = blockIdx.x & 3;           // 0..3 k splits
    int k0 = ks * KR;
    int tid = threadIdx.x;

    stage_x(x, xs, k0, tid);
    __syncthreads();

    int wave = tid >> 6;
    int lane = tid & 63;
    int col  = lane & 15;
    int kg   = lane >> 4;
    int r0 = rg * ROWS_PER_BLOCK + wave * 16;
    int r  = r0 + col;

    const int*   qrow = qw + (size_t)r * INF + k0 + kg * 8;
    const float* srow = scales + (size_t)r * (INF / 32) + (k0 >> 5);
    const short* aptr = xs + col * LDS_STRIDE + kg * 8;

    int4v A0 = *reinterpret_cast<const int4v*>(qrow);
    int4v B0 = *reinterpret_cast<const int4v*>(qrow + 4);
    int4v A1 = *reinterpret_cast<const int4v*>(qrow + 32);
    int4v B1 = *reinterpret_cast<const int4v*>(qrow + 36);
    float s0 = srow[0], s1 = srow[1];

    float4v acc = {0.f, 0.f, 0.f, 0.f};

    #pragma unroll 4
    for (int i = 0; i < NI; ++i) {
        int ip = (i + 2 < NI) ? (i + 2) : (NI - 1);
        int4v A2 = *reinterpret_cast<const int4v*>(qrow + ip * 32);
        int4v B2 = *reinterpret_cast<const int4v*>(qrow + ip * 32 + 4);
        float s2 = srow[ip];

        short8 bfrag = dequant8(A0, B0, s0);
        short8 afrag = *reinterpret_cast<const short8*>(aptr + i * 32);

        acc = __builtin_amdgcn_mfma_f32_16x16x32_bf16(afrag, bfrag, acc, 0, 0, 0);

        A0 = A1; B0 = B1; s0 = s1;
        A1 = A2; B1 = B2; s1 = s2;
    }

    // C mapping: col = lane&15 (out row r), row = (lane>>4)*4 + i (token t)
    float* pb = pbuf + (size_t)ks * TOK * OUTF;
    #pragma unroll
    for (int i = 0; i < 4; ++i) {
        int t = kg * 4 + i;
        pb[(size_t)t * OUTF + r0 + col] = acc[i];
    }
}

__global__ __launch_bounds__(256) void reduce_bias_k(
    const float* __restrict__ pbuf, const float* __restrict__ bias,
    float* __restrict__ out)
{
    int gid = blockIdx.x * 256 + threadIdx.x;   // 32768 threads, float4 each
    int f = gid * 4;
    int t = f >> 13;       // /8192
    int r = f & (OUTF - 1);
    float4v a = *reinterpret_cast<const float4v*>(bias + r);
    #pragma unroll
    for (int s = 0; s < KSPLIT; ++s) {
        float4v p = *reinterpret_cast<const float4v*>(pbuf + (size_t)(s * TOK + t) * OUTF + r);
        a += p;
    }
    *reinterpret_cast<float4v*>(out + f) = a;
}

// Fallback when d_ws is too small: full-K per block, direct write (+bias).
__global__ __launch_bounds__(256, 2) void gemm_q8_direct(
    const float* __restrict__ x, const int* __restrict__ qw,
    const float* __restrict__ scales, const float* __restrict__ bias,
    float* __restrict__ out)
{
    __shared__ short xs[TOK * LDS_STRIDE];
    int rg = blockIdx.x;               // 0..127
    int tid = threadIdx.x;
    int wave = tid >> 6;
    int lane = tid & 63;
    int col  = lane & 15;
    int kg   = lane >> 4;
    int r0 = rg * ROWS_PER_BLOCK + wave * 16;
    int r  = r0 + col;

    float4v acc = {0.f, 0.f, 0.f, 0.f};
    for (int ks = 0; ks < KSPLIT; ++ks) {
        int k0 = ks * KR;
        __syncthreads();
        stage_x(x, xs, k0, tid);
        __syncthreads();
        const int*   qrow = qw + (size_t)r * INF + k0 + kg * 8;
        const float* srow = scales + (size_t)r * (INF / 32) + (k0 >> 5);
        const short* aptr = xs + col * LDS_STRIDE + kg * 8;

        int4v A0 = *reinterpret_cast<const int4v*>(qrow);
        int4v B0 = *reinterpret_cast<const int4v*>(qrow + 4);
        int4v A1 = *reinterpret_cast<const int4v*>(qrow + 32);
        int4v B1 = *reinterpret_cast<const int4v*>(qrow + 36);
        float s0 = srow[0], s1 = srow[1];

        #pragma unroll 4
        for (int i = 0; i < NI; ++i) {
            int ip = (i + 2 < NI) ? (i + 2) : (NI - 1);
            int4v A2 = *reinterpret_cast<const int4v*>(qrow + ip * 32);
            int4v B2 = *reinterpret_cast<const int4v*>(qrow + ip * 32 + 4);
            float s2 = srow[ip];

            short8 bfrag = dequant8(A0, B0, s0);
            short8 afrag = *reinterpret_cast<const short8*>(aptr + i * 32);
            acc = __builtin_amdgcn_mfma_f32_16x16x32_bf16(afrag, bfrag, acc, 0, 0, 0);

            A0 = A1; B0 = B1; s0 = s1;
            A1 = A2; B1 = B2; s1 = s2;
        }
    }
    #pragma unroll
    for (int i = 0; i < 4; ++i) {
        int t = kg * 4 + i;
        out[(size_t)t * OUTF + r0 + col] = acc[i] + bias[r0 + col];
    }
}

extern "C" void kernel_launch(void* const* d_in, const int* in_sizes, int n_in,
                              void* d_out, int out_size, void* d_ws, size_t ws_size,
                              hipStream_t stream) {
    const float* x      = (const float*)d_in[0];
    const int*   qw     = (const int*)d_in[1];
    const float* scales = (const float*)d_in[2];
    const float* bias   = (const float*)d_in[3];
    float* out = (float*)d_out;

    size_t pbytes = (size_t)KSPLIT * TOK * OUTF * sizeof(float);   // 2 MB
    if (ws_size >= pbytes) {
        float* pbuf = (float*)d_ws;
        gemm_q8_part<<<NRG * KSPLIT, 256, 0, stream>>>(x, qw, scales, pbuf);
        reduce_bias_k<<<(TOK * OUTF / 4) / 256, 256, 0, stream>>>(pbuf, bias, out);
    } else {
        gemm_q8_direct<<<NRG, 256, 0, stream>>>(x, qw, scales, bias, out);
    }
}